// Round 20
// baseline (489.748 us; speedup 1.0000x reference)
//
#include <hip/hip_runtime.h>
#include <math.h>

#define DS_ 1024
#define DT_ 2048
#define V_  32000
#define SS_ 96
#define ST_ 128

// ---------------- small helpers ----------------

__device__ __forceinline__ float block_reduce_sum_256(float v) {
  __shared__ float tmp[4];
  #pragma unroll
  for (int off = 32; off; off >>= 1) v += __shfl_xor(v, off);
  const int wid = threadIdx.x >> 6;
  if ((threadIdx.x & 63) == 0) tmp[wid] = v;
  __syncthreads();
  if (threadIdx.x == 0) v = tmp[0] + tmp[1] + tmp[2] + tmp[3];
  return v;  // valid on thread 0 only
}

__device__ __forceinline__ const float* s_base(int b, const float* s_hq, const float* s_hp) {
  return (b < 8) ? (s_hq + (size_t)b * SS_ * DS_) : (s_hp + (size_t)(b - 8) * SS_ * DS_);
}
__device__ __forceinline__ const float* t_base(int b, const float* t_hq, const float* t_hp) {
  return (b < 8) ? (t_hq + (size_t)b * ST_ * DT_) : (t_hp + (size_t)(b - 8) * ST_ * DT_);
}

__device__ __forceinline__ unsigned short f2bf(float x) {  // RNE
  unsigned int u = __float_as_uint(x);
  u += 0x7fffu + ((u >> 16) & 1u);
  return (unsigned short)(u >> 16);
}
__device__ __forceinline__ float bf2f(unsigned short u) {
  return __uint_as_float(((unsigned int)u) << 16);
}

using bf16x8 = __attribute__((ext_vector_type(8))) short;
using f32x4  = __attribute__((ext_vector_type(4))) float;
using u16x4  = __attribute__((ext_vector_type(4))) unsigned short;

__device__ __forceinline__ void gll16(const void* g, void* l) {
  __builtin_amdgcn_global_load_lds((const __attribute__((address_space(1))) unsigned int*)g,
                                   (__attribute__((address_space(3))) unsigned int*)l, 16, 0, 0);
}

// VALU-only full-wave min of nonneg-float bit patterns; result valid in lane 63.
__device__ __forceinline__ unsigned int wave_umin_dpp(unsigned int r) {
  unsigned int t;
  t = (unsigned int)__builtin_amdgcn_update_dpp((int)r, (int)r, 0x111, 0xF, 0xF, false); r = r < t ? r : t;
  t = (unsigned int)__builtin_amdgcn_update_dpp((int)r, (int)r, 0x112, 0xF, 0xF, false); r = r < t ? r : t;
  t = (unsigned int)__builtin_amdgcn_update_dpp((int)r, (int)r, 0x114, 0xF, 0xF, false); r = r < t ? r : t;
  t = (unsigned int)__builtin_amdgcn_update_dpp((int)r, (int)r, 0x118, 0xF, 0xF, false); r = r < t ? r : t;
  t = (unsigned int)__builtin_amdgcn_update_dpp((int)r, (int)r, 0x142, 0xF, 0xF, false); r = r < t ? r : t;
  t = (unsigned int)__builtin_amdgcn_update_dpp((int)r, (int)r, 0x143, 0xF, 0xF, false); r = r < t ? r : t;
  return r;
}

// ---------------- bodies ----------------

__device__ __forceinline__ void scores_body(int blk, const float* __restrict__ sq,
                                            const float* __restrict__ sp,
                                            float* __restrict__ scores) {
  const int i = blk >> 3, j = blk & 7;
  float acc = 0.f;
  for (int k = threadIdx.x; k < DS_; k += 256)
    acc += sq[(size_t)i * DS_ + k] * sp[(size_t)j * DS_ + k];
  acc = block_reduce_sum_256(acc);
  if (threadIdx.x == 0) scores[i * 8 + j] = acc * 50.0f;  // 1/TEMP
}

__device__ __forceinline__ void proj2_body(int kc, const float* __restrict__ t_qry,
                                           const float* __restrict__ t_pos,
                                           const float* __restrict__ Wp,
                                           float* __restrict__ proj,
                                           unsigned char* smem) {
  float (*tv)[64] = (float (*)[64])smem;
  const int tid = threadIdx.x;
  for (int s = tid; s < 16 * 64; s += 256) {
    const int zi = s >> 6, k = s & 63;
    const float* t = (zi >= 8) ? (t_pos + (size_t)(zi - 8) * DT_) : (t_qry + (size_t)zi * DT_);
    tv[zi][k] = t[kc * 64 + k];
  }
  __syncthreads();
  const int d4 = tid * 4;
  float4 acc[16];
  #pragma unroll
  for (int zi = 0; zi < 16; ++zi) acc[zi] = (float4){0.f, 0.f, 0.f, 0.f};
  for (int k = 0; k < 64; ++k) {
    const float4 w = *(const float4*)&Wp[(size_t)(kc * 64 + k) * DS_ + d4];
    #pragma unroll
    for (int zi = 0; zi < 16; ++zi) {
      const float t = tv[zi][k];
      acc[zi].x += t * w.x; acc[zi].y += t * w.y;
      acc[zi].z += t * w.z; acc[zi].w += t * w.w;
    }
  }
  #pragma unroll
  for (int zi = 0; zi < 16; ++zi) {
    float* p = proj + (size_t)zi * DS_ + d4;
    atomicAdd(&p[0], acc[zi].x); atomicAdd(&p[1], acc[zi].y);
    atomicAdd(&p[2], acc[zi].z); atomicAdd(&p[3], acc[zi].w);
  }
}

__device__ __forceinline__ void norms_body(int blk, const float* __restrict__ s_hq,
                                           const float* __restrict__ s_hp,
                                           const float* __restrict__ t_hq,
                                           const float* __restrict__ t_hp,
                                           float* __restrict__ invn) {
  const int b = blk / 192, t = blk % 192;
  const float* bs = s_base(b, s_hq, s_hp);
  const float* bt = t_base(b, t_hq, t_hp);
  const float* row;
  int K;
  float* out;
  if (t < 32)       { row = bs + (size_t)t * DS_;             K = DS_; out = invn + b * 32 + t; }
  else if (t < 96)  { row = bs + (size_t)t * DS_;             K = DS_; out = invn + 512 + b * 64 + (t - 32); }
  else if (t < 128) { row = bt + (size_t)(t - 96 + 32) * DT_;  K = DT_; out = invn + 1536 + b * 32 + (t - 96); }
  else              { row = bt + (size_t)(t - 128 + 64) * DT_; K = DT_; out = invn + 2048 + b * 64 + (t - 128); }
  float ss = 0.f;
  for (int k = threadIdx.x; k < K; k += 256) { const float x = row[k]; ss += x * x; }
  ss = block_reduce_sum_256(ss);
  if (threadIdx.x == 0) *out = 1.0f / fmaxf(sqrtf(ss), 1e-8f);
}

__device__ __forceinline__ void pack_as_body(int g, const float* __restrict__ s_hq,
                                             const float* __restrict__ s_hp,
                                             unsigned short* __restrict__ As) {
  const int b = g >> 5, i = g & 31;
  const float* src = s_base(b, s_hq, s_hp) + (size_t)i * DS_;
  const int k4 = threadIdx.x * 4;
  const float4 w = *(const float4*)&src[k4];
  u16x4 o; o[0] = f2bf(w.x); o[1] = f2bf(w.y); o[2] = f2bf(w.z); o[3] = f2bf(w.w);
  *(u16x4*)&As[(size_t)g * DS_ + k4] = o;
}

__device__ __forceinline__ void pack_at_body(int g, const float* __restrict__ t_hq,
                                             const float* __restrict__ t_hp,
                                             unsigned short* __restrict__ At) {
  const int b = g >> 5, i = g & 31;
  const float* src = t_base(b, t_hq, t_hp) + (size_t)(32 + i) * DT_;
  #pragma unroll
  for (int it = 0; it < 2; ++it) {
    const int k4 = (threadIdx.x + it * 256) * 4;
    const float4 w = *(const float4*)&src[k4];
    u16x4 o; o[0] = f2bf(w.x); o[1] = f2bf(w.y); o[2] = f2bf(w.z); o[3] = f2bf(w.w);
    *(u16x4*)&At[(size_t)g * DT_ + k4] = o;
  }
}

// transpose + fp32->bf16, balanced granules: W[k][v] -> Wbt[v][k].
// Tile [128 k][128 v]; LDS bf16 [128][130] = 33280 B (4 blocks/CU).
// Stage: float4 coalesced (512 B/wave-instr), cvt in regs, ds_write_b64
// (2-way banks = free). Pack: thread=(v, k-half), ds_read_u16 broadcast
// pairs (conflict-free), 8 consecutive uint4 stores -> 256 B write granule.
__device__ __forceinline__ void convw5_body(int id, const float* __restrict__ W,
                                            unsigned short* __restrict__ Wbt,
                                            int K, unsigned char* smem) {
  unsigned short* tile = (unsigned short*)smem;   // [128][130] bf16
  const int v0 = (id % 250) * 128, k0 = (id / 250) * 128;
  const int tid = threadIdx.x;
  #pragma unroll
  for (int it = 0; it < 16; ++it) {
    const int s = it * 256 + tid;
    const int k = s >> 5, vl = s & 31;
    const float4 w = *(const float4*)&W[(size_t)(k0 + k) * V_ + v0 + vl * 4];
    u16x4 o; o[0] = f2bf(w.x); o[1] = f2bf(w.y); o[2] = f2bf(w.z); o[3] = f2bf(w.w);
    *(u16x4*)&tile[k * 130 + vl * 4] = o;
  }
  __syncthreads();
  const int v = tid & 127, kh = tid >> 7;   // k-half 0/1
  #pragma unroll
  for (int ch = 0; ch < 8; ++ch) {
    const int kb = kh * 64 + ch * 8;
    unsigned int o[4];
    #pragma unroll
    for (int q = 0; q < 4; ++q) {
      const unsigned int lo = tile[(kb + 2 * q) * 130 + v];
      const unsigned int hi = tile[(kb + 2 * q + 1) * 130 + v];
      o[q] = lo | (hi << 16);
    }
    uint4 pk = {o[0], o[1], o[2], o[3]};
    *(uint4*)&Wbt[(size_t)(v0 + v) * K + k0 + kb] = pk;
  }
}

// raw teacher dots: dtd[b][i][j] = dot(tv_i, tt_j)
__device__ __forceinline__ void dt_body(int id, const float* __restrict__ t_hq,
                                        const float* __restrict__ t_hp,
                                        float* __restrict__ dtd) {
  const int b = id >> 5, i = id & 31;
  const int wv = threadIdx.x >> 6, lane = threadIdx.x & 63;
  const float* bt = t_base(b, t_hq, t_hp);
  const float* a2p = bt + (size_t)(32 + i) * DT_;
  float a2[32];
  #pragma unroll
  for (int q = 0; q < 32; ++q) a2[q] = a2p[lane + 64 * q];
  for (int jj = 0; jj < 16; ++jj) {
    const int j = wv * 16 + jj;
    const float* b2 = bt + (size_t)(64 + j) * DT_;
    float dt = 0.f;
    #pragma unroll
    for (int q = 0; q < 32; ++q) dt += a2[q] * b2[lane + 64 * q];
    #pragma unroll
    for (int off = 32; off; off >>= 1) dt += __shfl_xor(dt, off);
    if (lane == 0) dtd[(b * 32 + i) * 64 + j] = dt;
  }
}

// raw student dots: csd[b][i][j] = dot(sv_i, st_j)
__device__ __forceinline__ void cs_body(int id, const float* __restrict__ s_hq,
                                        const float* __restrict__ s_hp,
                                        float* __restrict__ csd) {
  const int b = id >> 5, i = id & 31;
  const int wv = threadIdx.x >> 6, lane = threadIdx.x & 63;
  const float* bs = s_base(b, s_hq, s_hp);
  const float* a1p = bs + (size_t)i * DS_;
  float a1[16];
  #pragma unroll
  for (int q = 0; q < 16; ++q) a1[q] = a1p[lane + 64 * q];
  for (int jj = 0; jj < 16; ++jj) {
    const int j = wv * 16 + jj;
    const float* b1 = bs + (size_t)(32 + j) * DS_;
    float ds = 0.f;
    #pragma unroll
    for (int q = 0; q < 16; ++q) ds += a1[q] * b1[lane + 64 * q];
    #pragma unroll
    for (int off = 32; off; off >>= 1) ds += __shfl_xor(ds, off);
    if (lane == 0) csd[(b * 32 + i) * 64 + j] = ds;
  }
}

__device__ __forceinline__ void mse2_body(int blk, const float* __restrict__ s_qry,
                                          const float* __restrict__ s_pos,
                                          const float* __restrict__ proj,
                                          const float* __restrict__ bp,
                                          float* __restrict__ mse_acc) {
  const int z = blk >> 3, i = blk & 7;
  const float* s = (z ? s_pos : s_qry) + (size_t)i * DS_;
  const float* p = proj + ((size_t)z * 8 + i) * DS_;
  float ss = 0.f;
  for (int d = threadIdx.x; d < DS_; d += 256) {
    const float diff = s[d] - (p[d] + bp[d]);
    ss += diff * diff;
  }
  ss = block_reduce_sum_256(ss);
  if (threadIdx.x == 0) atomicAdd(mse_acc, ss);
}

// ---------------- GEMM body (counted-vmcnt schedule, stores bf16 logits) ----------------

template <int K>
__device__ __forceinline__ void gemm_body(int blk, int nwg,
                                          const unsigned short* __restrict__ A,
                                          const unsigned short* __restrict__ Wbt,
                                          unsigned short* __restrict__ Out,
                                          unsigned char* smem) {
  unsigned short* AldsB = (unsigned short*)smem;            // [2][8192]
  unsigned short* BldsB = (unsigned short*)(smem + 32768);  // [2][4096]
  // bijective XCD swizzle (m204)
  const int q = nwg >> 3, r = nwg & 7;
  const int xcd = blk & 7, off = blk >> 3;
  const int sblk = (xcd < r ? xcd * (q + 1) : r * (q + 1) + (xcd - r) * q) + off;
  const int m0 = (sblk & 1) * 256;
  const int n0 = (sblk >> 1) * 128;
  const int tid = threadIdx.x;
  const int wv = tid >> 6, lane = tid & 63;
  const int lr = lane & 15, cc = lane >> 4;

  f32x4 acc[4][8];
  #pragma unroll
  for (int mf = 0; mf < 4; ++mf)
    #pragma unroll
    for (int nf = 0; nf < 8; ++nf) acc[mf][nf] = (f32x4){0.f, 0.f, 0.f, 0.f};

  constexpr int NT = K / 32;

  auto stage = [&](int kt, int buf) {
    #pragma unroll
    for (int it = 0; it < 4; ++it) {
      const int slot = it * 256 + tid;
      const int row = slot >> 2, cs = slot & 3;
      gll16(A + (size_t)(m0 + row) * K + kt * 32 + ((cs ^ ((row >> 1) & 3)) << 3),
            AldsB + (size_t)buf * 8192 + (size_t)(it * 256 + wv * 64) * 8);
    }
    #pragma unroll
    for (int it = 0; it < 2; ++it) {
      const int slot = it * 256 + tid;
      const int row = slot >> 2, cs = slot & 3;
      gll16(Wbt + (size_t)(n0 + row) * K + kt * 32 + ((cs ^ ((row >> 1) & 3)) << 3),
            BldsB + (size_t)buf * 4096 + (size_t)(it * 256 + wv * 64) * 8);
    }
  };

  stage(0, 0);
  if (NT > 1) stage(1, 1);
  for (int kt = 0; kt < NT; ++kt) {
    const int cur = kt & 1;
    if (kt >= 1 && kt + 1 < NT) stage(kt + 1, cur ^ 1);
    if (kt + 1 < NT) asm volatile("s_waitcnt vmcnt(6)" ::: "memory");
    else             asm volatile("s_waitcnt vmcnt(0)" ::: "memory");
    asm volatile("s_barrier" ::: "memory");
    bf16x8 af[4];
    #pragma unroll
    for (int mf = 0; mf < 4; ++mf) {
      const int row = wv * 64 + mf * 16 + lr;
      af[mf] = *(const bf16x8*)(AldsB + cur * 8192 + row * 32 + ((cc ^ ((row >> 1) & 3)) << 3));
    }
    __builtin_amdgcn_s_setprio(1);
    #pragma unroll
    for (int nf = 0; nf < 8; ++nf) {
      const int vr = nf * 16 + lr;
      const bf16x8 bfr = *(const bf16x8*)(BldsB + cur * 4096 + vr * 32 + ((cc ^ ((vr >> 1) & 3)) << 3));
      #pragma unroll
      for (int mf = 0; mf < 4; ++mf)
        acc[mf][nf] = __builtin_amdgcn_mfma_f32_16x16x32_bf16(af[mf], bfr, acc[mf][nf], 0, 0, 0);
    }
    __builtin_amdgcn_s_setprio(0);
    asm volatile("s_barrier" ::: "memory");
  }

  unsigned short* Olds = AldsB;
  #pragma unroll
  for (int h = 0; h < 2; ++h) {
    if (h) __syncthreads();
    #pragma unroll
    for (int mf = 0; mf < 4; ++mf)
      #pragma unroll
      for (int nf4 = 0; nf4 < 4; ++nf4) {
        const int nf = h * 4 + nf4;
        #pragma unroll
        for (int q2 = 0; q2 < 4; ++q2) {
          const int row = wv * 64 + mf * 16 + (lane >> 4) * 4 + q2;
          const int col = nf4 * 16 + lr;
          Olds[row * 64 + (col ^ (((row >> 2) & 3) << 4))] = f2bf(acc[mf][nf][q2]);
        }
      }
    __syncthreads();
    #pragma unroll
    for (int it = 0; it < 4; ++it) {
      const int slot = it * 256 + tid;
      const int row = slot >> 3, c2 = slot & 7;
      const uint4 pk = *(const uint4*)&Olds[row * 64 + ((c2 ^ (((row >> 2) & 3) << 1)) << 3)];
      *(uint4*)&Out[(size_t)(m0 + row) * V_ + n0 + h * 64 + c2 * 8] = pk;
    }
  }
}

// ---------------- fused launches ----------------

// L0: convw5_T(4000) | convw5_S(2000) | scores(64) | proj2(32) | norms(3072) |
//     pack_as(512) | pack_at(512) | cs(512) | dt(512)   = 11216 blocks
__global__ __launch_bounds__(256) void fused_l0_kernel(const float* __restrict__ s_qry,
                                                       const float* __restrict__ s_pos,
                                                       const float* __restrict__ t_qry,
                                                       const float* __restrict__ t_pos,
                                                       const float* __restrict__ s_hq,
                                                       const float* __restrict__ s_hp,
                                                       const float* __restrict__ t_hq,
                                                       const float* __restrict__ t_hp,
                                                       const float* __restrict__ Ws,
                                                       const float* __restrict__ Wt,
                                                       const float* __restrict__ Wp,
                                                       float* __restrict__ scores,
                                                       float* __restrict__ proj,
                                                       float* __restrict__ invn,
                                                       unsigned short* __restrict__ As,
                                                       unsigned short* __restrict__ At,
                                                       unsigned short* __restrict__ Wsb,
                                                       unsigned short* __restrict__ Wtb,
                                                       float* __restrict__ csd,
                                                       float* __restrict__ dtd) {
  __shared__ __align__(16) unsigned char smem[33280];
  const int blk = blockIdx.x;
  if (blk < 4000)          convw5_body(blk, Wt, Wtb, DT_, smem);
  else if (blk < 6000)     convw5_body(blk - 4000, Ws, Wsb, DS_, smem);
  else if (blk < 6064)     scores_body(blk - 6000, s_qry, s_pos, scores);
  else if (blk < 6096)     proj2_body(blk - 6064, t_qry, t_pos, Wp, proj, smem);
  else if (blk < 9168)     norms_body(blk - 6096, s_hq, s_hp, t_hq, t_hp, invn);
  else if (blk < 9680)     pack_as_body(blk - 9168, s_hq, s_hp, As);
  else if (blk < 10192)    pack_at_body(blk - 9680, t_hq, t_hp, At);
  else if (blk < 10704)    cs_body(blk - 10192, s_hq, s_hp, csd);
  else                     dt_body(blk - 10704, t_hq, t_hp, dtd);
}

// L1: gemm_T(500) | gemm_S(500) | mse2(16)   = 1016 blocks
__global__ __launch_bounds__(256) void fused_l1_kernel(const unsigned short* __restrict__ As,
                                                       const unsigned short* __restrict__ Wsb,
                                                       unsigned short* __restrict__ Sg,
                                                       const unsigned short* __restrict__ At,
                                                       const unsigned short* __restrict__ Wtb,
                                                       unsigned short* __restrict__ Tg,
                                                       const float* __restrict__ s_qry,
                                                       const float* __restrict__ s_pos,
                                                       const float* __restrict__ proj,
                                                       const float* __restrict__ bp,
                                                       float* __restrict__ mse_acc) {
  __shared__ __align__(16) unsigned char smem[49152];
  const int blk = blockIdx.x;
  if (blk < 500)            gemm_body<DT_>(blk, 500, At, Wtb, Tg, smem);
  else if (blk < 1000)      gemm_body<DS_>(blk - 500, 500, As, Wsb, Sg, smem);
  else                      mse2_body(blk - 1000, s_qry, s_pos, proj, bp, mse_acc);
}

// ---------------- cost accumulation, LDS-staged ----------------

#define CPV 500
#define CPP 508

__global__ __launch_bounds__(256) void cost_pairs_kernel(const unsigned short* __restrict__ Sg,
                                                         const unsigned short* __restrict__ Tg,
                                                         float* __restrict__ cost1,
                                                         float* __restrict__ cost2) {
  __shared__ __align__(16) unsigned short Sl[32 * CPP];
  __shared__ __align__(16) unsigned short Tl[32 * CPP];
  const int b = blockIdx.x >> 6, sl = blockIdx.x & 63;
  const int v0 = sl * CPV;
  const int tid = threadIdx.x;

  for (int s = tid; s < 32 * 125; s += 256) {
    const int r = s / 125, c = s % 125;
    *(u16x4*)&Sl[r * CPP + c * 4] = *(const u16x4*)&Sg[(size_t)(b * 32 + r) * V_ + v0 + c * 4];
    *(u16x4*)&Tl[r * CPP + c * 4] = *(const u16x4*)&Tg[(size_t)(b * 32 + r) * V_ + v0 + c * 4];
  }
  __syncthreads();

  const int i = tid >> 3, j4 = (tid & 7) * 4;
  float a1[4] = {0.f, 0.f, 0.f, 0.f}, a2[4] = {0.f, 0.f, 0.f, 0.f};
  for (int v = 0; v < CPV; v += 4) {
    const u16x4 t4 = *(const u16x4*)&Tl[i * CPP + v];
    float tf[4];
    #pragma unroll
    for (int q = 0; q < 4; ++q) tf[q] = bf2f(t4[q]);
    #pragma unroll
    for (int jj = 0; jj < 4; ++jj) {
      const u16x4 s4 = *(const u16x4*)&Sl[(j4 + jj) * CPP + v];
      #pragma unroll
      for (int q = 0; q < 4; ++q) {
        const float d = tf[q] - bf2f(s4[q]);
        a1[jj] += fabsf(d);
        a2[jj] += d * d;
      }
    }
  }
  #pragma unroll
  for (int jj = 0; jj < 4; ++jj) {
    atomicAdd(&cost1[(size_t)b * 1024 + i * 32 + j4 + jj], a1[jj]);
    atomicAdd(&cost2[(size_t)b * 1024 + i * 32 + j4 + jj], a2[jj]);
  }
}

// ---------------- Hungarian + vlad fused ----------------

__global__ __launch_bounds__(256) void hung_vlad_kernel(const float* __restrict__ cost1,
                                                        const float* __restrict__ cost2,
                                                        const float* __restrict__ invn,
                                                        const float* __restrict__ csd,
                                                        const float* __restrict__ dtd,
                                                        float* __restrict__ vsd_acc,
                                                        float* __restrict__ vlad_acc) {
  const int b = blockIdx.x;
  const int tid = threadIdx.x;
  const float INF = __int_as_float(0x7f800000);
  __shared__ float C[32 * 33];
  __shared__ float u_lds[33];
  __shared__ int idx_lds[32];

  for (int s = tid; s < 1024; s += 256) {
    const int r = s >> 5, c = s & 31;
    C[r * 33 + c] = cost1[(size_t)b * 1024 + s];
  }
  if (tid == 0) u_lds[0] = 0.f;
  __syncthreads();
  if (tid < 32) {
    float m = C[tid * 33];
    for (int j = 1; j < 32; ++j) m = fminf(m, C[tid * 33 + j]);
    u_lds[tid + 1] = m;
  }
  __syncthreads();

  if (tid < 64) {   // wave 0 runs the assignment algorithm
    const int lane = tid;
    const bool isj = (lane >= 1 && lane <= 32);
    const int cix = isj ? (lane - 1) : 0;

    float v = 0.f;
    if (isj) {
      float m = INF;
      for (int i = 0; i < 32; ++i) m = fminf(m, C[i * 33 + cix] - u_lds[i + 1]);
      v = m;
    }

    int p = 0;
    unsigned int assigned = 0;
    for (int i = 1; i <= 32; ++i) {
      const float ui = u_lds[i];
      const bool zero = isj && (p == 0) && ((C[(i - 1) * 33 + cix] - ui) == v);
      const unsigned long long tie = __ballot(zero);
      if (tie) {
        const int j1 = __ffsll(tie) - 1;
        if (lane == j1) p = i;
        assigned |= (1u << (i - 1));
      }
    }

    for (int i = 1; i <= 32; ++i) {
      if (assigned & (1u << (i - 1))) continue;
      if (lane == 0) p = i;
      float minv = INF;
      int way = 0;
      int used = 0;
      int j0 = 0;
      float ui0 = u_lds[i];
      float crow = C[(i - 1) * 33 + cix];
      while (true) {
        if (lane == j0) used = 1;
        float val = INF;
        if (isj && !used) {
          const float cur = crow - ui0 - v;
          if (cur < minv) { minv = cur; way = j0; }
          val = minv;
        }
        const unsigned int rb = wave_umin_dpp(__float_as_uint(val));
        const unsigned int minb = (unsigned int)__builtin_amdgcn_readlane((int)rb, 63);
        const float delta = __uint_as_float(minb);
        const unsigned long long tie = __ballot(__float_as_uint(val) == minb);
        const int j1 = __ffsll(tie) - 1;
        const int i0n = __builtin_amdgcn_readlane(p, j1);
        const float ui0n = u_lds[i0n];
        const int nri = (i0n >= 1 ? i0n : 1) - 1;
        const float cnext = C[nri * 33 + cix];
        if (used) {
          u_lds[p] += delta;
          v -= delta;
        } else {
          minv -= delta;
        }
        j0 = j1;
        if (i0n == 0) break;
        ui0 = ui0n;
        crow = cnext;
      }
      while (j0) {
        const int j1 = __builtin_amdgcn_readlane(way, j0);
        const int pv = __builtin_amdgcn_readlane(p, j1);
        if (lane == j0) p = pv;
        j0 = j1;
      }
    }
    float term = 0.f;
    if (isj) {
      idx_lds[p - 1] = lane - 1;
      term = cost2[(size_t)b * 1024 + (p - 1) * 32 + (lane - 1)];
    }
    #pragma unroll
    for (int off = 32; off; off >>= 1) term += __shfl_xor(term, off);
    if (lane == 0) atomicAdd(vsd_acc, term);
  }
  __syncthreads();

  float local = 0.f;
  #pragma unroll
  for (int w = 0; w < 8; ++w) {
    const int cell = tid * 8 + w;
    const int i = cell >> 6, j = cell & 63;
    const int is = idx_lds[i];
    const float cs = csd[(b * 32 + is) * 64 + j] * invn[b * 32 + is] * invn[512 + b * 64 + j];
    const float ct = dtd[(b * 32 + i) * 64 + j] * invn[1536 + b * 32 + i] * invn[2048 + b * 64 + j];
    const float d = cs - ct;
    const float ad = fabsf(d);
    local += (ad < 1.f) ? 0.5f * d * d : ad - 0.5f;
  }
  local = block_reduce_sum_256(local);
  if (tid == 0) atomicAdd(vlad_acc, local);
}

// ---------------- finalize ----------------

__global__ __launch_bounds__(64) void final_kernel(const float* __restrict__ scores,
                                                   const float* __restrict__ accs,
                                                   float* __restrict__ out) {
  const int lane = threadIdx.x;
  float ci = 0.f;
  if (lane < 8) {
    float m = -1e30f;
    for (int j = 0; j < 8; ++j) m = fmaxf(m, scores[lane * 8 + j]);
    float sum = 0.f;
    for (int j = 0; j < 8; ++j) sum += expf(scores[lane * 8 + j] - m);
    const float lse = m + logf(sum);
    ci = scores[lane * 8 + lane] - lse;
  }
  #pragma unroll
  for (int off = 32; off; off >>= 1) ci += __shfl_xor(ci, off);
  if (lane == 0) {
    const float contrastive = -ci / 8.0f;
    const float mse = accs[0] / 16384.0f;
    const float vsd = accs[1] / 1024000.0f;
    const float vlad = accs[2] / 2048.0f;
    const float distill = (vsd + vlad) / 8.0f;
    out[0] = contrastive + mse + distill;
    out[1] = contrastive;
    out[2] = distill;
  }
}

// ---------------- launch ----------------

extern "C" void kernel_launch(void* const* d_in, const int* in_sizes, int n_in,
                              void* d_out, int out_size, void* d_ws, size_t ws_size,
                              hipStream_t stream) {
  const float* s_qry = (const float*)d_in[0];
  const float* s_pos = (const float*)d_in[1];
  const float* t_qry = (const float*)d_in[2];
  const float* t_pos = (const float*)d_in[3];
  const float* s_hq  = (const float*)d_in[4];
  const float* s_hp  = (const float*)d_in[5];
  const float* t_hq  = (const float*)d_in[6];
  const float* t_hp  = (const float*)d_in[7];
  const float* Ws    = (const float*)d_in[8];
  const float* Wt    = (const float*)d_in[9];
  const float* Wp    = (const float*)d_in[10];
  const float* bp    = (const float*)d_in[11];

  float* ws     = (float*)d_ws;
  float* scores = ws;                    // 64
  float* cost1  = ws + 64;               // 16384
  float* cost2  = ws + 16448;            // 16384
  float* invn   = ws + 32832;            // 3072
  float* accs   = ws + 35904;            // 4
  float* proj   = ws + 35908;            // 16384
  float* csd    = ws + 52292;            // 32768
  float* dtd    = ws + 85060;            // 32768 -> ends 117828
  const size_t small_bytes = (size_t)52292 * 4;   // zero through proj

  const size_t As_off = 524288;
  const size_t At_off = As_off + (size_t)512 * DS_ * 2;
  const size_t Ws_off = At_off + (size_t)512 * DT_ * 2;
  const size_t Wt_off = Ws_off + (size_t)V_ * DS_ * 2;
  const size_t Sg_off = Wt_off + (size_t)V_ * DT_ * 2;
  const size_t Tg_off = Sg_off + (size_t)512 * V_ * 2;
  const size_t req2   = Tg_off + (size_t)512 * V_ * 2;

  hipMemsetAsync(d_ws, 0, small_bytes, stream);

  if (ws_size >= req2) {
    unsigned short* As  = (unsigned short*)((char*)d_ws + As_off);
    unsigned short* At  = (unsigned short*)((char*)d_ws + At_off);
    unsigned short* Wsb = (unsigned short*)((char*)d_ws + Ws_off);
    unsigned short* Wtb = (unsigned short*)((char*)d_ws + Wt_off);
    unsigned short* Sg  = (unsigned short*)((char*)d_ws + Sg_off);
    unsigned short* Tg  = (unsigned short*)((char*)d_ws + Tg_off);

    fused_l0_kernel<<<11216, 256, 0, stream>>>(s_qry, s_pos, t_qry, t_pos,
                                               s_hq, s_hp, t_hq, t_hp,
                                               Ws, Wt, Wp, scores, proj, invn,
                                               As, At, Wsb, Wtb, csd, dtd);

    fused_l1_kernel<<<1016, 256, 0, stream>>>(As, Wsb, Sg, At, Wtb, Tg,
                                              s_qry, s_pos, proj, bp, accs + 0);

    cost_pairs_kernel<<<16 * 64, 256, 0, stream>>>(Sg, Tg, cost1, cost2);

    hung_vlad_kernel<<<16, 256, 0, stream>>>(cost1, cost2, invn, csd, dtd,
                                             accs + 1, accs + 2);
    final_kernel<<<1, 64, 0, stream>>>(scores, accs, (float*)d_out);
  }
}

// Round 21
// 428.132 us; speedup vs baseline: 1.1439x; 1.1439x over previous
//
#include <hip/hip_runtime.h>
#include <math.h>

#define DS_ 1024
#define DT_ 2048
#define V_  32000
#define SS_ 96
#define ST_ 128

// ---------------- small helpers ----------------

__device__ __forceinline__ float block_reduce_sum_256(float v) {
  __shared__ float tmp[4];
  #pragma unroll
  for (int off = 32; off; off >>= 1) v += __shfl_xor(v, off);
  const int wid = threadIdx.x >> 6;
  if ((threadIdx.x & 63) == 0) tmp[wid] = v;
  __syncthreads();
  if (threadIdx.x == 0) v = tmp[0] + tmp[1] + tmp[2] + tmp[3];
  return v;  // valid on thread 0 only
}

__device__ __forceinline__ const float* s_base(int b, const float* s_hq, const float* s_hp) {
  return (b < 8) ? (s_hq + (size_t)b * SS_ * DS_) : (s_hp + (size_t)(b - 8) * SS_ * DS_);
}
__device__ __forceinline__ const float* t_base(int b, const float* t_hq, const float* t_hp) {
  return (b < 8) ? (t_hq + (size_t)b * ST_ * DT_) : (t_hp + (size_t)(b - 8) * ST_ * DT_);
}

__device__ __forceinline__ unsigned short f2bf(float x) {  // RNE
  unsigned int u = __float_as_uint(x);
  u += 0x7fffu + ((u >> 16) & 1u);
  return (unsigned short)(u >> 16);
}
__device__ __forceinline__ float bf2f(unsigned short u) {
  return __uint_as_float(((unsigned int)u) << 16);
}

using bf16x8 = __attribute__((ext_vector_type(8))) short;
using f32x4  = __attribute__((ext_vector_type(4))) float;
using u16x4  = __attribute__((ext_vector_type(4))) unsigned short;

__device__ __forceinline__ void gll16(const void* g, void* l) {
  __builtin_amdgcn_global_load_lds((const __attribute__((address_space(1))) unsigned int*)g,
                                   (__attribute__((address_space(3))) unsigned int*)l, 16, 0, 0);
}

// VALU-only full-wave min of nonneg-float bit patterns; result valid in lane 63.
__device__ __forceinline__ unsigned int wave_umin_dpp(unsigned int r) {
  unsigned int t;
  t = (unsigned int)__builtin_amdgcn_update_dpp((int)r, (int)r, 0x111, 0xF, 0xF, false); r = r < t ? r : t;
  t = (unsigned int)__builtin_amdgcn_update_dpp((int)r, (int)r, 0x112, 0xF, 0xF, false); r = r < t ? r : t;
  t = (unsigned int)__builtin_amdgcn_update_dpp((int)r, (int)r, 0x114, 0xF, 0xF, false); r = r < t ? r : t;
  t = (unsigned int)__builtin_amdgcn_update_dpp((int)r, (int)r, 0x118, 0xF, 0xF, false); r = r < t ? r : t;
  t = (unsigned int)__builtin_amdgcn_update_dpp((int)r, (int)r, 0x142, 0xF, 0xF, false); r = r < t ? r : t;
  t = (unsigned int)__builtin_amdgcn_update_dpp((int)r, (int)r, 0x143, 0xF, 0xF, false); r = r < t ? r : t;
  return r;
}

// ---------------- bodies ----------------

__device__ __forceinline__ void scores_body(int blk, const float* __restrict__ sq,
                                            const float* __restrict__ sp,
                                            float* __restrict__ scores) {
  const int i = blk >> 3, j = blk & 7;
  float acc = 0.f;
  for (int k = threadIdx.x; k < DS_; k += 256)
    acc += sq[(size_t)i * DS_ + k] * sp[(size_t)j * DS_ + k];
  acc = block_reduce_sum_256(acc);
  if (threadIdx.x == 0) scores[i * 8 + j] = acc * 50.0f;  // 1/TEMP
}

__device__ __forceinline__ void proj2_body(int kc, const float* __restrict__ t_qry,
                                           const float* __restrict__ t_pos,
                                           const float* __restrict__ Wp,
                                           float* __restrict__ proj,
                                           unsigned char* smem) {
  float (*tv)[64] = (float (*)[64])smem;
  const int tid = threadIdx.x;
  for (int s = tid; s < 16 * 64; s += 256) {
    const int zi = s >> 6, k = s & 63;
    const float* t = (zi >= 8) ? (t_pos + (size_t)(zi - 8) * DT_) : (t_qry + (size_t)zi * DT_);
    tv[zi][k] = t[kc * 64 + k];
  }
  __syncthreads();
  const int d4 = tid * 4;
  float4 acc[16];
  #pragma unroll
  for (int zi = 0; zi < 16; ++zi) acc[zi] = (float4){0.f, 0.f, 0.f, 0.f};
  for (int k = 0; k < 64; ++k) {
    const float4 w = *(const float4*)&Wp[(size_t)(kc * 64 + k) * DS_ + d4];
    #pragma unroll
    for (int zi = 0; zi < 16; ++zi) {
      const float t = tv[zi][k];
      acc[zi].x += t * w.x; acc[zi].y += t * w.y;
      acc[zi].z += t * w.z; acc[zi].w += t * w.w;
    }
  }
  #pragma unroll
  for (int zi = 0; zi < 16; ++zi) {
    float* p = proj + (size_t)zi * DS_ + d4;
    atomicAdd(&p[0], acc[zi].x); atomicAdd(&p[1], acc[zi].y);
    atomicAdd(&p[2], acc[zi].z); atomicAdd(&p[3], acc[zi].w);
  }
}

__device__ __forceinline__ void norms_body(int blk, const float* __restrict__ s_hq,
                                           const float* __restrict__ s_hp,
                                           const float* __restrict__ t_hq,
                                           const float* __restrict__ t_hp,
                                           float* __restrict__ invn) {
  const int b = blk / 192, t = blk % 192;
  const float* bs = s_base(b, s_hq, s_hp);
  const float* bt = t_base(b, t_hq, t_hp);
  const float* row;
  int K;
  float* out;
  if (t < 32)       { row = bs + (size_t)t * DS_;             K = DS_; out = invn + b * 32 + t; }
  else if (t < 96)  { row = bs + (size_t)t * DS_;             K = DS_; out = invn + 512 + b * 64 + (t - 32); }
  else if (t < 128) { row = bt + (size_t)(t - 96 + 32) * DT_;  K = DT_; out = invn + 1536 + b * 32 + (t - 96); }
  else              { row = bt + (size_t)(t - 128 + 64) * DT_; K = DT_; out = invn + 2048 + b * 64 + (t - 128); }
  float ss = 0.f;
  for (int k = threadIdx.x; k < K; k += 256) { const float x = row[k]; ss += x * x; }
  ss = block_reduce_sum_256(ss);
  if (threadIdx.x == 0) *out = 1.0f / fmaxf(sqrtf(ss), 1e-8f);
}

__device__ __forceinline__ void pack_as_body(int g, const float* __restrict__ s_hq,
                                             const float* __restrict__ s_hp,
                                             unsigned short* __restrict__ As) {
  const int b = g >> 5, i = g & 31;
  const float* src = s_base(b, s_hq, s_hp) + (size_t)i * DS_;
  const int k4 = threadIdx.x * 4;
  const float4 w = *(const float4*)&src[k4];
  u16x4 o; o[0] = f2bf(w.x); o[1] = f2bf(w.y); o[2] = f2bf(w.z); o[3] = f2bf(w.w);
  *(u16x4*)&As[(size_t)g * DS_ + k4] = o;
}

__device__ __forceinline__ void pack_at_body(int g, const float* __restrict__ t_hq,
                                             const float* __restrict__ t_hp,
                                             unsigned short* __restrict__ At) {
  const int b = g >> 5, i = g & 31;
  const float* src = t_base(b, t_hq, t_hp) + (size_t)(32 + i) * DT_;
  #pragma unroll
  for (int it = 0; it < 2; ++it) {
    const int k4 = (threadIdx.x + it * 256) * 4;
    const float4 w = *(const float4*)&src[k4];
    u16x4 o; o[0] = f2bf(w.x); o[1] = f2bf(w.y); o[2] = f2bf(w.z); o[3] = f2bf(w.w);
    *(u16x4*)&At[(size_t)g * DT_ + k4] = o;
  }
}

__device__ __forceinline__ void convw_body(int id, const float* __restrict__ W,
                                           unsigned short* __restrict__ Wbt,
                                           int K, unsigned char* smem) {
  float (*tile)[65] = (float (*)[65])smem;
  const int v0 = (id % 500) * 64, k0 = (id / 500) * 64;
  const int tid = threadIdx.x;
  #pragma unroll
  for (int it = 0; it < 4; ++it) {
    const int kr = (tid >> 4) + it * 16;
    const int v4 = (tid & 15) * 4;
    const float4 w = *(const float4*)&W[(size_t)(k0 + kr) * V_ + v0 + v4];
    tile[v4 + 0][kr] = w.x; tile[v4 + 1][kr] = w.y;
    tile[v4 + 2][kr] = w.z; tile[v4 + 3][kr] = w.w;
  }
  __syncthreads();
  #pragma unroll
  for (int it = 0; it < 2; ++it) {
    const int s = tid + it * 256;
    const int v = s >> 3, ch = s & 7;
    const float* src = &tile[v][ch * 8];
    unsigned int o[4];
    #pragma unroll
    for (int q = 0; q < 4; ++q)
      o[q] = (unsigned int)f2bf(src[2 * q]) | ((unsigned int)f2bf(src[2 * q + 1]) << 16);
    uint4 pk = {o[0], o[1], o[2], o[3]};
    *(uint4*)&Wbt[(size_t)(v0 + v) * K + k0 + ch * 8] = pk;
  }
}

// raw teacher dots: dtd[b][i][j] = dot(tv_i, tt_j)
__device__ __forceinline__ void dt_body(int id, const float* __restrict__ t_hq,
                                        const float* __restrict__ t_hp,
                                        float* __restrict__ dtd) {
  const int b = id >> 5, i = id & 31;
  const int wv = threadIdx.x >> 6, lane = threadIdx.x & 63;
  const float* bt = t_base(b, t_hq, t_hp);
  const float* a2p = bt + (size_t)(32 + i) * DT_;
  float a2[32];
  #pragma unroll
  for (int q = 0; q < 32; ++q) a2[q] = a2p[lane + 64 * q];
  for (int jj = 0; jj < 16; ++jj) {
    const int j = wv * 16 + jj;
    const float* b2 = bt + (size_t)(64 + j) * DT_;
    float dt = 0.f;
    #pragma unroll
    for (int q = 0; q < 32; ++q) dt += a2[q] * b2[lane + 64 * q];
    #pragma unroll
    for (int off = 32; off; off >>= 1) dt += __shfl_xor(dt, off);
    if (lane == 0) dtd[(b * 32 + i) * 64 + j] = dt;
  }
}

// raw student dots: csd[b][i][j] = dot(sv_i, st_j)
__device__ __forceinline__ void cs_body(int id, const float* __restrict__ s_hq,
                                        const float* __restrict__ s_hp,
                                        float* __restrict__ csd) {
  const int b = id >> 5, i = id & 31;
  const int wv = threadIdx.x >> 6, lane = threadIdx.x & 63;
  const float* bs = s_base(b, s_hq, s_hp);
  const float* a1p = bs + (size_t)i * DS_;
  float a1[16];
  #pragma unroll
  for (int q = 0; q < 16; ++q) a1[q] = a1p[lane + 64 * q];
  for (int jj = 0; jj < 16; ++jj) {
    const int j = wv * 16 + jj;
    const float* b1 = bs + (size_t)(32 + j) * DS_;
    float ds = 0.f;
    #pragma unroll
    for (int q = 0; q < 16; ++q) ds += a1[q] * b1[lane + 64 * q];
    #pragma unroll
    for (int off = 32; off; off >>= 1) ds += __shfl_xor(ds, off);
    if (lane == 0) csd[(b * 32 + i) * 64 + j] = ds;
  }
}

__device__ __forceinline__ void mse2_body(int blk, const float* __restrict__ s_qry,
                                          const float* __restrict__ s_pos,
                                          const float* __restrict__ proj,
                                          const float* __restrict__ bp,
                                          float* __restrict__ mse_acc) {
  const int z = blk >> 3, i = blk & 7;
  const float* s = (z ? s_pos : s_qry) + (size_t)i * DS_;
  const float* p = proj + ((size_t)z * 8 + i) * DS_;
  float ss = 0.f;
  for (int d = threadIdx.x; d < DS_; d += 256) {
    const float diff = s[d] - (p[d] + bp[d]);
    ss += diff * diff;
  }
  ss = block_reduce_sum_256(ss);
  if (threadIdx.x == 0) atomicAdd(mse_acc, ss);
}

// ---------------- GEMM body (counted-vmcnt schedule, stores bf16 logits) ----------------

template <int K>
__device__ __forceinline__ void gemm_body(int blk, int nwg,
                                          const unsigned short* __restrict__ A,
                                          const unsigned short* __restrict__ Wbt,
                                          unsigned short* __restrict__ Out,
                                          unsigned char* smem) {
  unsigned short* AldsB = (unsigned short*)smem;            // [2][8192]
  unsigned short* BldsB = (unsigned short*)(smem + 32768);  // [2][4096]
  // bijective XCD swizzle (m204)
  const int q = nwg >> 3, r = nwg & 7;
  const int xcd = blk & 7, off = blk >> 3;
  const int sblk = (xcd < r ? xcd * (q + 1) : r * (q + 1) + (xcd - r) * q) + off;
  const int m0 = (sblk & 1) * 256;
  const int n0 = (sblk >> 1) * 128;
  const int tid = threadIdx.x;
  const int wv = tid >> 6, lane = tid & 63;
  const int lr = lane & 15, cc = lane >> 4;

  f32x4 acc[4][8];
  #pragma unroll
  for (int mf = 0; mf < 4; ++mf)
    #pragma unroll
    for (int nf = 0; nf < 8; ++nf) acc[mf][nf] = (f32x4){0.f, 0.f, 0.f, 0.f};

  constexpr int NT = K / 32;

  auto stage = [&](int kt, int buf) {
    #pragma unroll
    for (int it = 0; it < 4; ++it) {
      const int slot = it * 256 + tid;
      const int row = slot >> 2, cs = slot & 3;
      gll16(A + (size_t)(m0 + row) * K + kt * 32 + ((cs ^ ((row >> 1) & 3)) << 3),
            AldsB + (size_t)buf * 8192 + (size_t)(it * 256 + wv * 64) * 8);
    }
    #pragma unroll
    for (int it = 0; it < 2; ++it) {
      const int slot = it * 256 + tid;
      const int row = slot >> 2, cs = slot & 3;
      gll16(Wbt + (size_t)(n0 + row) * K + kt * 32 + ((cs ^ ((row >> 1) & 3)) << 3),
            BldsB + (size_t)buf * 4096 + (size_t)(it * 256 + wv * 64) * 8);
    }
  };

  stage(0, 0);
  if (NT > 1) stage(1, 1);
  for (int kt = 0; kt < NT; ++kt) {
    const int cur = kt & 1;
    if (kt >= 1 && kt + 1 < NT) stage(kt + 1, cur ^ 1);
    if (kt + 1 < NT) asm volatile("s_waitcnt vmcnt(6)" ::: "memory");
    else             asm volatile("s_waitcnt vmcnt(0)" ::: "memory");
    asm volatile("s_barrier" ::: "memory");
    bf16x8 af[4];
    #pragma unroll
    for (int mf = 0; mf < 4; ++mf) {
      const int row = wv * 64 + mf * 16 + lr;
      af[mf] = *(const bf16x8*)(AldsB + cur * 8192 + row * 32 + ((cc ^ ((row >> 1) & 3)) << 3));
    }
    __builtin_amdgcn_s_setprio(1);
    #pragma unroll
    for (int nf = 0; nf < 8; ++nf) {
      const int vr = nf * 16 + lr;
      const bf16x8 bfr = *(const bf16x8*)(BldsB + cur * 4096 + vr * 32 + ((cc ^ ((vr >> 1) & 3)) << 3));
      #pragma unroll
      for (int mf = 0; mf < 4; ++mf)
        acc[mf][nf] = __builtin_amdgcn_mfma_f32_16x16x32_bf16(af[mf], bfr, acc[mf][nf], 0, 0, 0);
    }
    __builtin_amdgcn_s_setprio(0);
    asm volatile("s_barrier" ::: "memory");
  }

  unsigned short* Olds = AldsB;
  #pragma unroll
  for (int h = 0; h < 2; ++h) {
    if (h) __syncthreads();
    #pragma unroll
    for (int mf = 0; mf < 4; ++mf)
      #pragma unroll
      for (int nf4 = 0; nf4 < 4; ++nf4) {
        const int nf = h * 4 + nf4;
        #pragma unroll
        for (int q2 = 0; q2 < 4; ++q2) {
          const int row = wv * 64 + mf * 16 + (lane >> 4) * 4 + q2;
          const int col = nf4 * 16 + lr;
          Olds[row * 64 + (col ^ (((row >> 2) & 3) << 4))] = f2bf(acc[mf][nf][q2]);
        }
      }
    __syncthreads();
    #pragma unroll
    for (int it = 0; it < 4; ++it) {
      const int slot = it * 256 + tid;
      const int row = slot >> 3, c2 = slot & 7;
      const uint4 pk = *(const uint4*)&Olds[row * 64 + ((c2 ^ (((row >> 2) & 3) << 1)) << 3)];
      *(uint4*)&Out[(size_t)(m0 + row) * V_ + n0 + h * 64 + c2 * 8] = pk;
    }
  }
}

// ---------------- fused launches ----------------

// PRE: scores(64) | proj2(32) | norms(3072) | pack_as(512) | pack_at(512) |
//      convw_S(8000) | cs(512) | dt(512)
__global__ __launch_bounds__(256) void fused_pre_kernel(const float* __restrict__ s_qry,
                                                        const float* __restrict__ s_pos,
                                                        const float* __restrict__ t_qry,
                                                        const float* __restrict__ t_pos,
                                                        const float* __restrict__ s_hq,
                                                        const float* __restrict__ s_hp,
                                                        const float* __restrict__ t_hq,
                                                        const float* __restrict__ t_hp,
                                                        const float* __restrict__ Ws,
                                                        const float* __restrict__ Wp,
                                                        float* __restrict__ scores,
                                                        float* __restrict__ proj,
                                                        float* __restrict__ invn,
                                                        unsigned short* __restrict__ As,
                                                        unsigned short* __restrict__ At,
                                                        unsigned short* __restrict__ Wsb,
                                                        float* __restrict__ csd,
                                                        float* __restrict__ dtd) {
  __shared__ __align__(16) unsigned char smem[16640];
  const int blk = blockIdx.x;
  if (blk < 64)            scores_body(blk, s_qry, s_pos, scores);
  else if (blk < 96)       proj2_body(blk - 64, t_qry, t_pos, Wp, proj, smem);
  else if (blk < 3168)     norms_body(blk - 96, s_hq, s_hp, t_hq, t_hp, invn);
  else if (blk < 3680)     pack_as_body(blk - 3168, s_hq, s_hp, As);
  else if (blk < 4192)     pack_at_body(blk - 3680, t_hq, t_hp, At);
  else if (blk < 12192)    convw_body(blk - 4192, Ws, Wsb, DS_, smem);
  else if (blk < 12704)    cs_body(blk - 12192, s_hq, s_hp, csd);
  else                     dt_body(blk - 12704, t_hq, t_hp, dtd);
}

// MID: gemm_S(500) | convw_T(16000) | mse2(16)
__global__ __launch_bounds__(256) void fused_mid_kernel(const unsigned short* __restrict__ As,
                                                        const unsigned short* __restrict__ Wsb,
                                                        unsigned short* __restrict__ Sg,
                                                        const float* __restrict__ Wt,
                                                        unsigned short* __restrict__ Wtb,
                                                        const float* __restrict__ s_qry,
                                                        const float* __restrict__ s_pos,
                                                        const float* __restrict__ proj,
                                                        const float* __restrict__ bp,
                                                        float* __restrict__ mse_acc) {
  __shared__ __align__(16) unsigned char smem[49152];
  const int blk = blockIdx.x;
  if (blk < 500)            gemm_body<DS_>(blk, 500, As, Wsb, Sg, smem);
  else if (blk < 16500)     convw_body(blk - 500, Wt, Wtb, DT_, smem);
  else                      mse2_body(blk - 16500, s_qry, s_pos, proj, bp, mse_acc);
}

__global__ __launch_bounds__(256) void gemm_tn_kernel_t(const unsigned short* __restrict__ A,
                                                        const unsigned short* __restrict__ Wbt,
                                                        unsigned short* __restrict__ Out) {
  __shared__ __align__(16) unsigned char smem[49152];
  gemm_body<DT_>(blockIdx.x, (int)gridDim.x, A, Wbt, Out, smem);
}

// ---------------- cost accumulation, LDS-staged ----------------

#define CPV 500
#define CPP 508

__global__ __launch_bounds__(256) void cost_pairs_kernel(const unsigned short* __restrict__ Sg,
                                                         const unsigned short* __restrict__ Tg,
                                                         float* __restrict__ cost1,
                                                         float* __restrict__ cost2) {
  __shared__ __align__(16) unsigned short Sl[32 * CPP];
  __shared__ __align__(16) unsigned short Tl[32 * CPP];
  const int b = blockIdx.x >> 6, sl = blockIdx.x & 63;
  const int v0 = sl * CPV;
  const int tid = threadIdx.x;

  for (int s = tid; s < 32 * 125; s += 256) {
    const int r = s / 125, c = s % 125;
    *(u16x4*)&Sl[r * CPP + c * 4] = *(const u16x4*)&Sg[(size_t)(b * 32 + r) * V_ + v0 + c * 4];
    *(u16x4*)&Tl[r * CPP + c * 4] = *(const u16x4*)&Tg[(size_t)(b * 32 + r) * V_ + v0 + c * 4];
  }
  __syncthreads();

  const int i = tid >> 3, j4 = (tid & 7) * 4;
  float a1[4] = {0.f, 0.f, 0.f, 0.f}, a2[4] = {0.f, 0.f, 0.f, 0.f};
  for (int v = 0; v < CPV; v += 4) {
    const u16x4 t4 = *(const u16x4*)&Tl[i * CPP + v];
    float tf[4];
    #pragma unroll
    for (int q = 0; q < 4; ++q) tf[q] = bf2f(t4[q]);
    #pragma unroll
    for (int jj = 0; jj < 4; ++jj) {
      const u16x4 s4 = *(const u16x4*)&Sl[(j4 + jj) * CPP + v];
      #pragma unroll
      for (int q = 0; q < 4; ++q) {
        const float d = tf[q] - bf2f(s4[q]);
        a1[jj] += fabsf(d);
        a2[jj] += d * d;
      }
    }
  }
  #pragma unroll
  for (int jj = 0; jj < 4; ++jj) {
    atomicAdd(&cost1[(size_t)b * 1024 + i * 32 + j4 + jj], a1[jj]);
    atomicAdd(&cost2[(size_t)b * 1024 + i * 32 + j4 + jj], a2[jj]);
  }
}

// ---------------- K4: Hungarian — JV warm start + DPP Dijkstra ----------------

__global__ __launch_bounds__(64) void hungarian_kernel(const float* __restrict__ cost1,
                                                       const float* __restrict__ cost2,
                                                       int* __restrict__ idx,
                                                       float* __restrict__ vsd_acc) {
  const int b = blockIdx.x;
  const int lane = threadIdx.x;
  const float INF = __int_as_float(0x7f800000);
  __shared__ float C[32 * 33];
  __shared__ float u_lds[33];

  for (int s = lane; s < 1024; s += 64) {
    const int r = s >> 5, c = s & 31;
    C[r * 33 + c] = cost1[(size_t)b * 1024 + s];
  }
  if (lane == 0) u_lds[0] = 0.f;
  __syncthreads();

  const bool isj = (lane >= 1 && lane <= 32);
  const int cix = isj ? (lane - 1) : 0;

  if (lane < 32) {
    float m = C[lane * 33];
    for (int j = 1; j < 32; ++j) m = fminf(m, C[lane * 33 + j]);
    u_lds[lane + 1] = m;
  }
  __syncthreads();

  float v = 0.f;
  if (isj) {
    float m = INF;
    for (int i = 0; i < 32; ++i) m = fminf(m, C[i * 33 + cix] - u_lds[i + 1]);
    v = m;
  }

  int p = 0;
  unsigned int assigned = 0;
  for (int i = 1; i <= 32; ++i) {
    const float ui = u_lds[i];
    const bool zero = isj && (p == 0) && ((C[(i - 1) * 33 + cix] - ui) == v);
    const unsigned long long tie = __ballot(zero);
    if (tie) {
      const int j1 = __ffsll(tie) - 1;
      if (lane == j1) p = i;
      assigned |= (1u << (i - 1));
    }
  }

  for (int i = 1; i <= 32; ++i) {
    if (assigned & (1u << (i - 1))) continue;
    if (lane == 0) p = i;
    float minv = INF;
    int way = 0;
    int used = 0;
    int j0 = 0;
    float ui0 = u_lds[i];
    float crow = C[(i - 1) * 33 + cix];
    while (true) {
      if (lane == j0) used = 1;
      float val = INF;
      if (isj && !used) {
        const float cur = crow - ui0 - v;
        if (cur < minv) { minv = cur; way = j0; }
        val = minv;
      }
      const unsigned int rb = wave_umin_dpp(__float_as_uint(val));
      const unsigned int minb = (unsigned int)__builtin_amdgcn_readlane((int)rb, 63);
      const float delta = __uint_as_float(minb);
      const unsigned long long tie = __ballot(__float_as_uint(val) == minb);
      const int j1 = __ffsll(tie) - 1;
      const int i0n = __builtin_amdgcn_readlane(p, j1);
      const float ui0n = u_lds[i0n];
      const int nri = (i0n >= 1 ? i0n : 1) - 1;
      const float cnext = C[nri * 33 + cix];
      if (used) {
        u_lds[p] += delta;
        v -= delta;
      } else {
        minv -= delta;
      }
      j0 = j1;
      if (i0n == 0) break;
      ui0 = ui0n;
      crow = cnext;
    }
    while (j0) {
      const int j1 = __builtin_amdgcn_readlane(way, j0);
      const int pv = __builtin_amdgcn_readlane(p, j1);
      if (lane == j0) p = pv;
      j0 = j1;
    }
  }
  float term = 0.f;
  if (isj) {
    idx[b * 32 + (p - 1)] = lane - 1;
    term = cost2[(size_t)b * 1024 + (p - 1) * 32 + (lane - 1)];
  }
  #pragma unroll
  for (int off = 32; off; off >>= 1) term += __shfl_xor(term, off);
  if (lane == 0) atomicAdd(vsd_acc, term);
}

// ---------------- vlad gather (tiny) ----------------

__global__ __launch_bounds__(256) void vlad_gather_kernel(const int* __restrict__ idx,
                                                          const float* __restrict__ invn,
                                                          const float* __restrict__ csd,
                                                          const float* __restrict__ dtd,
                                                          float* __restrict__ vlad_acc) {
  const int b = blockIdx.x;
  float local = 0.f;
  #pragma unroll
  for (int w = 0; w < 8; ++w) {
    const int cell = threadIdx.x * 8 + w;   // 2048 cells = 32 i x 64 j
    const int i = cell >> 6, j = cell & 63;
    const int is = idx[b * 32 + i];
    const float cs = csd[(b * 32 + is) * 64 + j] * invn[b * 32 + is] * invn[512 + b * 64 + j];
    const float ct = dtd[(b * 32 + i) * 64 + j] * invn[1536 + b * 32 + i] * invn[2048 + b * 64 + j];
    const float d = cs - ct;
    const float ad = fabsf(d);
    local += (ad < 1.f) ? 0.5f * d * d : ad - 0.5f;
  }
  local = block_reduce_sum_256(local);
  if (threadIdx.x == 0) atomicAdd(vlad_acc, local);
}

// ---------------- K7: finalize ----------------

__global__ __launch_bounds__(64) void final_kernel(const float* __restrict__ scores,
                                                   const float* __restrict__ accs,
                                                   float* __restrict__ out) {
  const int lane = threadIdx.x;
  float ci = 0.f;
  if (lane < 8) {
    float m = -1e30f;
    for (int j = 0; j < 8; ++j) m = fmaxf(m, scores[lane * 8 + j]);
    float sum = 0.f;
    for (int j = 0; j < 8; ++j) sum += expf(scores[lane * 8 + j] - m);
    const float lse = m + logf(sum);
    ci = scores[lane * 8 + lane] - lse;
  }
  #pragma unroll
  for (int off = 32; off; off >>= 1) ci += __shfl_xor(ci, off);
  if (lane == 0) {
    const float contrastive = -ci / 8.0f;
    const float mse = accs[0] / 16384.0f;
    const float vsd = accs[1] / 1024000.0f;
    const float vlad = accs[2] / 2048.0f;
    const float distill = (vsd + vlad) / 8.0f;
    out[0] = contrastive + mse + distill;
    out[1] = contrastive;
    out[2] = distill;
  }
}

// ---------------- launch ----------------

extern "C" void kernel_launch(void* const* d_in, const int* in_sizes, int n_in,
                              void* d_out, int out_size, void* d_ws, size_t ws_size,
                              hipStream_t stream) {
  const float* s_qry = (const float*)d_in[0];
  const float* s_pos = (const float*)d_in[1];
  const float* t_qry = (const float*)d_in[2];
  const float* t_pos = (const float*)d_in[3];
  const float* s_hq  = (const float*)d_in[4];
  const float* s_hp  = (const float*)d_in[5];
  const float* t_hq  = (const float*)d_in[6];
  const float* t_hp  = (const float*)d_in[7];
  const float* Ws    = (const float*)d_in[8];
  const float* Wt    = (const float*)d_in[9];
  const float* Wp    = (const float*)d_in[10];
  const float* bp    = (const float*)d_in[11];

  float* ws     = (float*)d_ws;
  float* scores = ws;                    // 64
  float* cost1  = ws + 64;               // 16384
  float* cost2  = ws + 16448;            // 16384
  float* invn   = ws + 32832;            // 3072
  float* accs   = ws + 35904;            // 4
  float* proj   = ws + 35908;            // 16384
  int*   idx    = (int*)(ws + 52292);    // 512 ints -> ends 52804
  float* csd    = ws + 52804;            // 32768 -> ends 85572
  float* dtd    = ws + 85572;            // 32768 -> ends 118340
  const size_t small_bytes = (size_t)52804 * 4;   // zero through idx

  const size_t As_off = 524288;
  const size_t At_off = As_off + (size_t)512 * DS_ * 2;
  const size_t Ws_off = At_off + (size_t)512 * DT_ * 2;
  const size_t Wt_off = Ws_off + (size_t)V_ * DS_ * 2;
  const size_t Sg_off = Wt_off + (size_t)V_ * DT_ * 2;
  const size_t Tg_off = Sg_off + (size_t)512 * V_ * 2;
  const size_t req2   = Tg_off + (size_t)512 * V_ * 2;

  hipMemsetAsync(d_ws, 0, small_bytes, stream);

  if (ws_size >= req2) {
    unsigned short* As  = (unsigned short*)((char*)d_ws + As_off);
    unsigned short* At  = (unsigned short*)((char*)d_ws + At_off);
    unsigned short* Wsb = (unsigned short*)((char*)d_ws + Ws_off);
    unsigned short* Wtb = (unsigned short*)((char*)d_ws + Wt_off);
    unsigned short* Sg  = (unsigned short*)((char*)d_ws + Sg_off);
    unsigned short* Tg  = (unsigned short*)((char*)d_ws + Tg_off);

    fused_pre_kernel<<<13216, 256, 0, stream>>>(s_qry, s_pos, t_qry, t_pos,
                                                s_hq, s_hp, t_hq, t_hp,
                                                Ws, Wp, scores, proj, invn,
                                                As, At, Wsb, csd, dtd);

    fused_mid_kernel<<<16516, 256, 0, stream>>>(As, Wsb, Sg, Wt, Wtb,
                                                s_qry, s_pos, proj, bp, accs + 0);

    gemm_tn_kernel_t<<<(V_ / 128) * 2, 256, 0, stream>>>(At, Wtb, Tg);
    cost_pairs_kernel<<<16 * 64, 256, 0, stream>>>(Sg, Tg, cost1, cost2);

    hungarian_kernel<<<16, 64, 0, stream>>>(cost1, cost2, idx, accs + 1);
    vlad_gather_kernel<<<16, 256, 0, stream>>>(idx, invn, csd, dtd, accs + 2);
    final_kernel<<<1, 64, 0, stream>>>(scores, accs, (float*)d_out);
  }
}